// Round 9
// baseline (821.795 us; speedup 1.0000x reference)
//
#include <hip/hip_runtime.h>
#include <math.h>

// Problem constants (reference: B=32, L=2048)
#define LLEN 2048
#define BATCH 32
#define N_PTS (LLEN - 2)     // 2046 embedded points
#define N_DEATH (LLEN - 3)   // 2045 MST edges / deaths
#define SORT_N 2048
#define TPB 256              // 4 waves, one per SIMD
#define PT 8                 // elements per thread
#define NW 4                 // waves per block
#define BIG 1e30f

// Wave64 unsigned-min via DPP (VALU pipe). Result valid in lane 63.
__device__ __forceinline__ unsigned dpp_umin6(unsigned v) {
    unsigned t;
    t = (unsigned)__builtin_amdgcn_update_dpp(-1, (int)v, 0x111, 0xF, 0xF, false); // row_shr:1
    v = t < v ? t : v;
    t = (unsigned)__builtin_amdgcn_update_dpp(-1, (int)v, 0x112, 0xF, 0xF, false); // row_shr:2
    v = t < v ? t : v;
    t = (unsigned)__builtin_amdgcn_update_dpp(-1, (int)v, 0x114, 0xF, 0xF, false); // row_shr:4
    v = t < v ? t : v;
    t = (unsigned)__builtin_amdgcn_update_dpp(-1, (int)v, 0x118, 0xF, 0xF, false); // row_shr:8
    v = t < v ? t : v;
    t = (unsigned)__builtin_amdgcn_update_dpp(-1, (int)v, 0x142, 0xF, 0xF, false); // row_bcast:15
    v = t < v ? t : v;
    t = (unsigned)__builtin_amdgcn_update_dpp(-1, (int)v, 0x143, 0xF, 0xF, false); // row_bcast:31
    v = t < v ? t : v;
    return v;
}

// One block per series. Prim with packed (d2|idx) u32 candidates; lock-free
// polled LDS mailbox — r5 protocol (proven 751 us topo):
//   * b32 slots, lane-63 publishes straight off the DPP chain.
//   * bit-11 sentinel clear prevents all-visited-wave tag corruption.
//   * double-buffer (i&1) + tag parity ((i>>1)&1) separate i / i-1 / i-2;
//     reader progress rules out i-4. DS ops complete in-order per wave.
// ROUND-9 DELTA (theory: LDS-pipe self-contention — 4 spinning waves' poll
// loads crowd the single per-CU LDS pipe, delaying the very publishes they
// wait on): the 4 mailbox slots are 16 contiguous aligned bytes, so the poll
// is now ONE ds_read_b128 per retry instead of four ds_read_b32 — 4x less
// poll traffic at identical latency. Scan reverted to the exact r5 scalar
// form (r8's float2 packing measured +26 us).
__global__ __launch_bounds__(TPB)
void topo_kernel(const float* __restrict__ pred,
                 const float* __restrict__ tgt,
                 float* __restrict__ topo /* [64][N_DEATH] */) {
    __shared__ float4 pp[SORT_N];
    __shared__ float deaths[SORT_N];                  // raw d2 during Prim
    __shared__ __align__(16) unsigned xslot[2 * NW];  // mailbox [buf][wave]

    const int b = blockIdx.x;
    const float* x = (b < BATCH) ? (pred + b * LLEN) : (tgt + (b - BATCH) * LLEN);
    const int t = threadIdx.x;
    const int lane = t & 63;
    const int wid = t >> 6;

    // mailbox init: tag bit = 1 mismatches iteration 0/1's expected tag 0
    if (t < 2 * NW) xslot[t] = 0x800u;

    float px[PT], py[PT], pz[PT];
    unsigned m[PT];      // packed running min-distance (d2_hi20 | 0 | idx)
    unsigned idxs[PT];
    unsigned vis = 0;    // bit s: vertex t*PT+s is visited (or padding)
#pragma unroll
    for (int s = 0; s < PT; ++s) {
        int idx = t * PT + s;
        idxs[s] = (unsigned)idx;
        bool valid = idx < N_PTS;
        px[s] = valid ? x[idx]     : 0.f;
        py[s] = valid ? x[idx + 1] : 0.f;
        pz[s] = valid ? x[idx + 2] : 0.f;
        pp[idx] = make_float4(px[s], py[s], pz[s], 0.f);
        m[s] = 0x7F800000u | idxs[s];           // +inf packed
        if (!valid || idx == 0) vis |= 1u << s; // pads + start vertex visited
    }
    __syncthreads();   // pp[] + mailbox init visible (only barrier before sort)

    float pjx = x[0], pjy = x[1], pjz = x[2];

    for (int i = 0; i < N_DEATH; ++i) {
        // fused: min-update with distance to j + masked local argmin.
        unsigned lv0 = 0xFFFFFFFFu, lv1 = 0xFFFFFFFFu;
#pragma unroll
        for (int s = 0; s < PT; ++s) {
            float dx = px[s] - pjx, dy = py[s] - pjy, dz = pz[s] - pjz;
            float d2 = dx * dx + dy * dy + dz * dz;
            unsigned pk = (__float_as_uint(d2) & 0xFFFFF000u) | idxs[s]; // v_and_or
            unsigned nm = m[s] < pk ? m[s] : pk;
            m[s] = nm;
            unsigned ext = (unsigned)__builtin_amdgcn_sbfe((int)vis, s, 1);
            unsigned cand = nm | ext;
            if (s & 1) lv1 = lv1 < cand ? lv1 : cand;
            else       lv0 = lv0 < cand ? lv0 : cand;
        }
        unsigned lv = lv0 < lv1 ? lv0 : lv1;
        unsigned wmin = dpp_umin6(lv);           // valid in lane 63
        const unsigned tag = ((unsigned)(i >> 1) & 1u) << 11;
        const int base = (i & 1) * NW;
        // lane 63 publishes straight away: clear bit 11 (all-visited sentinel
        // protection), stamp tag.
        if (lane == 63) {
            unsigned clean = (wmin & 0xFFFFF7FFu) | tag;
            __hip_atomic_store(&xslot[base + wid], clean,
                               __ATOMIC_RELAXED, __HIP_MEMORY_SCOPE_WORKGROUP);
        }
        // poll: ONE ds_read_b128 covers all 4 slots (16B aligned). Per-slot
        // u32s can't tear; "memory" clobber forces a fresh read per retry.
        const uint4* slot4 = (const uint4*)&xslot[base];
        uint4 v;
        for (;;) {
            __asm__ __volatile__("" ::: "memory");
            v = *slot4;
            unsigned bad = ((v.x ^ tag) | (v.y ^ tag) |
                            (v.z ^ tag) | (v.w ^ tag)) & 0x800u;
            if (!bad) break;
        }
        unsigned w01 = v.x < v.y ? v.x : v.y;
        unsigned w23 = v.z < v.w ? v.z : v.w;
        unsigned win = w01 < w23 ? w01 : w23;
        int j = (int)(win & 0x7FFu);
        // mark new j visited in its owner thread
        vis |= (t == (j >> 3)) ? (1u << (j & 7)) : 0u;
        float4 pj = pp[j];                       // broadcast read, conflict-free
        pjx = pj.x; pjy = pj.y; pjz = pj.z;
        if (t == 0) deaths[i] = __uint_as_float(win & 0xFFFFF000u); // raw d2
    }

    // pad then bitonic sort DESCENDING on d2 (sqrt is monotone -> same order)
    if (t < SORT_N - N_DEATH) deaths[N_DEATH + t] = -BIG;
    __syncthreads();

    for (int k = 2; k <= SORT_N; k <<= 1) {
        for (int jj = k >> 1; jj > 0; jj >>= 1) {
#pragma unroll
            for (int s = 0; s < SORT_N / TPB; ++s) {
                int ii = t + s * TPB;
                int ixj = ii ^ jj;
                if (ixj > ii) {
                    float a = deaths[ii], c = deaths[ixj];
                    bool descBlock = ((ii & k) == 0);
                    bool doSwap = descBlock ? (a < c) : (a > c);
                    if (doSwap) { deaths[ii] = c; deaths[ixj] = a; }
                }
            }
            __syncthreads();
        }
    }

    for (int e = t; e < N_DEATH; e += TPB)
        topo[b * N_DEATH + e] = sqrtf(deaths[e]);   // sqrt deferred to here
}

// Two-stage loss (used when d_ws has room for the 512 B partials buffer)
__global__ __launch_bounds__(256)
void partial_loss(const float* __restrict__ pred,
                  const float* __restrict__ tgt,
                  const float* __restrict__ topo,
                  float2* __restrict__ part) {
    const int t = threadIdx.x;
    const int gid = blockIdx.x * 256 + t;       // 0..16383
    const float4* p4 = (const float4*)pred;
    const float4* t4 = (const float4*)tgt;
    float4 a = p4[gid], c = t4[gid];            // exactly one float4 per thread
    float dx = a.x - c.x, dy = a.y - c.y, dz = a.z - c.z, dw = a.w - c.w;
    float msum = dx * dx + dy * dy + dz * dz + dw * dw;
    float tsum = 0.f;
    const int nt = BATCH * N_DEATH;             // 65440
    for (int e = gid; e < nt; e += 64 * 256) {
        float d = topo[e] - topo[e + nt];
        tsum += d * d;
    }
    __shared__ float sm[2][4];
#pragma unroll
    for (int off = 32; off >= 1; off >>= 1) {
        msum += __shfl_xor(msum, off);
        tsum += __shfl_xor(tsum, off);
    }
    int lane = t & 63, wid = t >> 6;
    if (lane == 0) { sm[0][wid] = msum; sm[1][wid] = tsum; }
    __syncthreads();
    if (t == 0) {
        float M = 0.f, T = 0.f;
#pragma unroll
        for (int w = 0; w < 4; ++w) { M += sm[0][w]; T += sm[1][w]; }
        part[blockIdx.x] = make_float2(M, T);
    }
}

__global__ __launch_bounds__(64)
void final_loss(const float2* __restrict__ part, float* __restrict__ out) {
    const int t = threadIdx.x;
    float2 p = part[t];
    float M = p.x, T = p.y;
#pragma unroll
    for (int off = 32; off >= 1; off >>= 1) {
        M += __shfl_xor(M, off);
        T += __shfl_xor(T, off);
    }
    if (t == 0)
        out[0] = M / (float)(BATCH * LLEN) + 0.1f * (T / (float)(BATCH * N_DEATH));
}

// Fallback: single-block deterministic reduction (no extra scratch needed)
#define RTPB 1024
__global__ __launch_bounds__(RTPB)
void loss_kernel(const float* __restrict__ pred,
                 const float* __restrict__ tgt,
                 const float* __restrict__ topo,
                 float* __restrict__ out) {
    const int t = threadIdx.x;
    float msum = 0.f;
    const float4* p4 = (const float4*)pred;
    const float4* t4 = (const float4*)tgt;
    const int n4 = (BATCH * LLEN) / 4;   // 16384
    for (int e = t; e < n4; e += RTPB) {
        float4 a = p4[e], c = t4[e];
        float dx = a.x - c.x, dy = a.y - c.y, dz = a.z - c.z, dw = a.w - c.w;
        msum += dx * dx + dy * dy + dz * dz + dw * dw;
    }
    float tsum = 0.f;
    const int nt = BATCH * N_DEATH;      // 65440
    for (int e = t; e < nt; e += RTPB) {
        float d = topo[e] - topo[e + nt];
        tsum += d * d;
    }
    __shared__ float sm[2][RTPB / 64];
#pragma unroll
    for (int off = 32; off >= 1; off >>= 1) {
        msum += __shfl_xor(msum, off);
        tsum += __shfl_xor(tsum, off);
    }
    int lane = t & 63, wid = t >> 6;
    if (lane == 0) { sm[0][wid] = msum; sm[1][wid] = tsum; }
    __syncthreads();
    if (t == 0) {
        float M = 0.f, T = 0.f;
#pragma unroll
        for (int w = 0; w < RTPB / 64; ++w) { M += sm[0][w]; T += sm[1][w]; }
        out[0] = M / (float)(BATCH * LLEN) + 0.1f * (T / (float)nt);
    }
}

extern "C" void kernel_launch(void* const* d_in, const int* in_sizes, int n_in,
                              void* d_out, int out_size, void* d_ws, size_t ws_size,
                              hipStream_t stream) {
    const float* pred = (const float*)d_in[0];
    const float* tgt  = (const float*)d_in[1];
    const size_t topo_bytes = (size_t)64 * N_DEATH * 4;   // 523,520 B
    float* topo = (float*)d_ws;

    topo_kernel<<<2 * BATCH, TPB, 0, stream>>>(pred, tgt, topo);

    if (ws_size >= topo_bytes + 64 * sizeof(float2)) {
        float2* part = (float2*)((char*)d_ws + topo_bytes);
        partial_loss<<<64, 256, 0, stream>>>(pred, tgt, topo, part);
        final_loss<<<1, 64, 0, stream>>>(part, (float*)d_out);
    } else {
        loss_kernel<<<1, RTPB, 0, stream>>>(pred, tgt, topo, (float*)d_out);
    }
}